// Round 5
// baseline (201.275 us; speedup 1.0000x reference)
//
#include <hip/hip_runtime.h>
#include <cstdint>
#include <cstddef>

typedef unsigned short u16;
typedef __attribute__((ext_vector_type(8))) short short8;
typedef __attribute__((ext_vector_type(4))) float f32x4;

#define CIN   512
#define COUT  512
#define BATCH 16
#define HWSZ  1024      // 32*32
#define PADW  34        // 32 + 2 halo

static constexpr float MOD_SCALE  = 0.044194173824159216f;   // 1/sqrt(512)
static constexpr float CONV_SCALE = 0.014731391274719739f;   // 1/sqrt(512*9)

// workspace layout (bytes)
#define WS_S    0                              // 8192 f32   (32 KB)
#define WS_DSC  (32*1024)                      // 8192 f32   (32 KB)
#define WS_WSQ  (64*1024)                      // 262144 f32 (1 MB)
#define WS_WBT  (64*1024 + 1024*1024)          // 9*512*512 bf16 (4.5 MB)
#define WS_XSP  (WS_WBT + 9*512*512*2)         // 16*34*34*512 bf16 (~18 MB)

__device__ __forceinline__ u16 f2bf(float f) {
  union { float f; uint32_t u; } v; v.f = f;
  uint32_t r = v.u + 0x7fffu + ((v.u >> 16) & 1u);   // RNE
  return (u16)(r >> 16);
}

__device__ __forceinline__ void gload16(const void* g, void* l) {
  __builtin_amdgcn_global_load_lds(
      (const __attribute__((address_space(1))) void*)g,
      (__attribute__((address_space(3))) void*)l, 16, 0, 0);
}

// ---------------- s[b,i] = mod_scale * style[b,:] . mod_w[i,:] + mod_b[i] ----------------
__global__ void k_style(const float* __restrict__ style, const float* __restrict__ mod_w,
                        const float* __restrict__ mod_b, float* __restrict__ s_out) {
  int gid  = blockIdx.x * blockDim.x + threadIdx.x;
  int w    = gid >> 6, lane = gid & 63;
  int b    = w >> 9, i = w & 511;
  const float4* st = (const float4*)(style + (size_t)b * 512);
  const float4* mw = (const float4*)(mod_w + (size_t)i * 512);
  float4 a0 = st[lane * 2], a1 = st[lane * 2 + 1];
  float4 w0 = mw[lane * 2], w1 = mw[lane * 2 + 1];
  float acc = a0.x*w0.x + a0.y*w0.y + a0.z*w0.z + a0.w*w0.w
            + a1.x*w1.x + a1.y*w1.y + a1.z*w1.z + a1.w*w1.w;
  #pragma unroll
  for (int off = 32; off; off >>= 1) acc += __shfl_xor(acc, off);
  if (lane == 0) s_out[w] = acc * MOD_SCALE + mod_b[i];
}

// ---------------- fused: wsq[o,i] = sum_k w^2 ; wbT[kxy][o][i] = bf16(w) ----------------
__global__ void k_wprep(const float* __restrict__ w, float* __restrict__ wsq,
                        u16* __restrict__ wbt) {
  int idx = blockIdx.x * 256 + threadIdx.x;          // 262144 = o*512+i
  const float* p = w + (size_t)idx * 9;
  float a = 0.f;
  #pragma unroll
  for (int kxy = 0; kxy < 9; ++kxy) {
    float v = p[kxy];
    a += v * v;
    wbt[(size_t)kxy * 262144 + idx] = f2bf(v);
  }
  wsq[idx] = a;
}

// ---------------- dscale[b,o] = conv_scale * rsqrt(cs^2 * sum_i wsq[o,i]*s[b,i]^2 + 1e-8) ----
__global__ void k_dscale(const float* __restrict__ wsq, const float* __restrict__ s,
                         float* __restrict__ dsc) {
  int gid  = blockIdx.x * blockDim.x + threadIdx.x;
  int w    = gid >> 6, lane = gid & 63;
  int b    = w >> 9, o = w & 511;
  const float4* q4 = (const float4*)(wsq + (size_t)o * 512);
  const float4* s4 = (const float4*)(s   + (size_t)b * 512);
  float4 q0 = q4[lane * 2], q1 = q4[lane * 2 + 1];
  float4 t0 = s4[lane * 2], t1 = s4[lane * 2 + 1];
  float acc = q0.x*t0.x*t0.x + q0.y*t0.y*t0.y + q0.z*t0.z*t0.z + q0.w*t0.w*t0.w
            + q1.x*t1.x*t1.x + q1.y*t1.y*t1.y + q1.z*t1.z*t1.z + q1.w*t1.w*t1.w;
  #pragma unroll
  for (int off = 32; off; off >>= 1) acc += __shfl_xor(acc, off);
  if (lane == 0)
    dsc[w] = CONV_SCALE * rsqrtf(acc * CONV_SCALE * CONV_SCALE + 1e-8f);
}

// ---------------- zero only the halo border of xs_p (replaces 18MB memset) ----------------
__global__ void k_halo(u16* __restrict__ xsp) {
  int cell = blockIdx.x;      // 0..131 border cells of the 34x34 grid
  int b = blockIdx.y;
  int y, x;
  if (cell < 34)       { y = 0;          x = cell; }
  else if (cell < 68)  { y = 33;         x = cell - 34; }
  else if (cell < 100) { y = cell - 67;  x = 0; }    // 1..32
  else                 { y = cell - 99;  x = 33; }   // 1..32
  uint32_t* p = (uint32_t*)(xsp + ((size_t)(b * PADW + y) * PADW + x) * 512);
  p[threadIdx.x] = 0;   // 256 threads x 4B = 512 u16
}

// ---------------- xs_p[b][y+1][x+1][i] = bf16(x[b][i][y][x] * s[b][i])  (NCHW->NHWC) --------
__global__ void k_xs(const float* __restrict__ x, const float* __restrict__ s,
                     u16* __restrict__ xsp) {
  __shared__ float tile[64][33];
  int icb = blockIdx.x, y = blockIdx.y, b = blockIdx.z;
  int t = threadIdx.x;
  int i0 = icb * 64;
  int c  = t & 31;       // x coord
  int r0 = t >> 5;       // 0..7
  #pragma unroll
  for (int it = 0; it < 8; ++it) {
    int row = r0 + it * 8;                           // i_loc 0..63
    float sv = s[b * 512 + i0 + row];
    tile[row][c] = x[((size_t)(b * 512 + i0 + row)) * 1024 + y * 32 + c] * sv;
  }
  __syncthreads();
  int il = t & 63;
  int x0 = t >> 6;       // 0..3
  #pragma unroll
  for (int it = 0; it < 8; ++it) {
    int xc = x0 + it * 4;
    xsp[((size_t)((b * PADW + y + 1) * PADW) + (xc + 1)) * 512 + i0 + il] = f2bf(tile[il][xc]);
  }
}

// ---------------- implicit-GEMM conv + fused epilogue ----------------
// Tile 256(o) x 128(m). 8 waves in 2 K-parity groups (grp = wave>>2):
// group g computes K-steps with (ks&1)==g; per-wave output 128x64 (pos = wave&3).
// Wave w and w+4 share a SIMD -> natural producer/consumer anti-phase:
// while one wave runs a pure-MFMA burst (64 MFMA from registers, setprio'd),
// the other pre-reads its next tile's 24 fragments from LDS + issues staging.
// Tri-buffered LDS, counted vmcnt(6) (never 0 in main loop). T2 swizzle kept.
// Epilogue: group-1 partial accumulators reduced into group-0 via LDS.
__global__ __launch_bounds__(512, 2) void k_conv(
    const u16* __restrict__ wbt, const u16* __restrict__ xsp,
    const float* __restrict__ dsc, const float* __restrict__ noise,
    const float* __restrict__ nw, const float* __restrict__ abias,
    float* __restrict__ out)
{
  __shared__ u16 SM[73728];   // 147456 B: A bufs [0,49152) u16, B bufs [49152,73728)

  const int tid  = threadIdx.x;
  const int wave = tid >> 6, lane = tid & 63;
  const int grp  = wave >> 2;          // K-parity group (0: even ks, 1: odd ks)
  const int pos  = wave & 3;           // output sub-tile position
  const int wo = (pos >> 1) * 128;     // o sub-block: 0/128
  const int wm = (pos & 1) * 64;       // m sub-block: 0/64

  // T1: XCD swizzle (grid 256 = 8 XCD x 32 contiguous tiles)
  const int bid = blockIdx.x;
  const int swz = (bid & 7) * 32 + (bid >> 3);
  const int o0 = (swz >> 7) << 8;     // 0 or 256
  const int m0 = (swz & 127) << 7;    // 0..16256
  const int b  = m0 >> 10;            // uniform per block

  // staging bases: lane covers row (base + lane>>3), 16-B chunk (lane&7);
  // swizzled source chunk = (lane&7) ^ (row&7)   [T2, write side via global src]
  const int cc = (((lane & 7) ^ (lane >> 3)) * 8);
  const u16* gA[4]; int lAo[4];
  #pragma unroll
  for (int q = 0; q < 4; ++q) {
    int r = wave * 32 + q * 8 + (lane >> 3);          // 0..255
    gA[q] = wbt + (size_t)(o0 + r) * 512 + cc;
    lAo[q] = (wave * 32 + q * 8) * 64;                // wave-uniform LDS dest
  }
  const u16* gB[2]; int lBo[2];
  #pragma unroll
  for (int q = 0; q < 2; ++q) {
    int r = wave * 16 + q * 8 + (lane >> 3);          // 0..127
    int mg = m0 + r;
    int yy = (mg >> 5) & 31, xx = mg & 31;
    gB[q] = xsp + ((size_t)(b * PADW + yy) * PADW + xx) * 512 + cc;
    lBo[q] = (wave * 16 + q * 8) * 64;
  }

  f32x4 acc[8][4];
  #pragma unroll
  for (int i = 0; i < 8; ++i)
    #pragma unroll
    for (int j = 0; j < 4; ++j) acc[i][j] = (f32x4){0.f, 0.f, 0.f, 0.f};

  const int lrow = lane & 15;
  const int lk   = (lane >> 4) * 8;
  const int rsw  = (lrow & 7) << 3;   // read-side swizzle (u16 units)
  const int kos0 = lk ^ rsw;
  const int kos1 = (32 + lk) ^ rsw;

  short8 avp[2][8], bvp[2][4];        // pre-read fragments (96 VGPR)

  auto stage = [&](int ks, int bufi) {
    int sa = bufi * 16384, sb = 49152 + bufi * 8192;
    int kxy = ks >> 3, ib = (ks & 7) << 6;
    int ky = kxy / 3, kx = kxy - ky * 3;
    int offA = kxy * 262144 + ib;
    int offB = ((ky * PADW + kx) << 9) + ib;
    #pragma unroll
    for (int q = 0; q < 4; ++q) gload16(gA[q] + offA, &SM[sa + lAo[q]]);
    #pragma unroll
    for (int q = 0; q < 2; ++q) gload16(gB[q] + offB, &SM[sb + lBo[q]]);
  };

  auto preread = [&](int bufi) {
    int ca = bufi * 16384, cb = 49152 + bufi * 8192;
    #pragma unroll
    for (int mi = 0; mi < 8; ++mi) {
      avp[0][mi] = *(const short8*)&SM[ca + (wo + mi * 16 + lrow) * 64 + kos0];
      avp[1][mi] = *(const short8*)&SM[ca + (wo + mi * 16 + lrow) * 64 + kos1];
    }
    #pragma unroll
    for (int ni = 0; ni < 4; ++ni) {
      bvp[0][ni] = *(const short8*)&SM[cb + (wm + ni * 16 + lrow) * 64 + kos0];
      bvp[1][ni] = *(const short8*)&SM[cb + (wm + ni * 16 + lrow) * 64 + kos1];
    }
  };

  auto compute = [&]() {
    __builtin_amdgcn_s_setprio(1);
    #pragma unroll
    for (int kh = 0; kh < 2; ++kh)
      #pragma unroll
      for (int mi = 0; mi < 8; ++mi)
        #pragma unroll
        for (int ni = 0; ni < 4; ++ni)
          acc[mi][ni] = __builtin_amdgcn_mfma_f32_16x16x32_bf16(
              avp[kh][mi], bvp[kh][ni], acc[mi][ni], 0, 0, 0);
    __builtin_amdgcn_s_setprio(0);
  };

  // prologue: two tiles staged, group0 pre-reads tile 0
  stage(0, 0);
  stage(1, 1);
  asm volatile("s_waitcnt vmcnt(6)" ::: "memory");   // stage(0) landed
  __builtin_amdgcn_s_barrier();
  if (grp == 0) preread(0);

  // Per step ks: stage(ks+2) [buf (ks+2)%3, WAR-safe: last reads were pre-reads
  // 2 steps + 2 barriers ago]; vmcnt(6) [stage(ks+1) landed, stage(ks+2) in
  // flight]; barrier; computing group runs pure-MFMA burst from registers,
  // other group pre-reads tile ks+1 from buf (ks+1)%3.
#define STEP(KS, BPRE, BNXT, WN, DOSTAGE, PREOK)                         \
  {                                                                      \
    if (DOSTAGE) stage((KS) + 2, BNXT);                                  \
    asm volatile("s_waitcnt vmcnt(" #WN ")" ::: "memory");               \
    __builtin_amdgcn_s_barrier();                                        \
    if (grp == ((KS) & 1)) compute();                                    \
    else if (PREOK) preread(BPRE);                                       \
  }

  for (int t = 0; t < 11; ++t) {
    const int k0 = t * 6;
    STEP(k0 + 0, 1, 2, 6, 1, 1);
    STEP(k0 + 1, 2, 0, 6, 1, 1);
    STEP(k0 + 2, 0, 1, 6, 1, 1);
    STEP(k0 + 3, 1, 2, 6, 1, 1);
    STEP(k0 + 4, 2, 0, 6, 1, 1);
    STEP(k0 + 5, 0, 1, 6, 1, 1);
  }
  // tail k0 = 66
  STEP(66, 1, 2, 6, 1, 1);
  STEP(67, 2, 0, 6, 1, 1);
  STEP(68, 0, 1, 6, 1, 1);
  STEP(69, 1, 2, 6, 1, 1);
  STEP(70, 2, 0, 0, 0, 1);   // vmcnt(0): stage(71) must land for tile-71 pre-read
  STEP(71, 0, 1, 0, 0, 0);
#undef STEP

  // ---- cross-group accumulator reduction via LDS (reuse SM as f32 scratch) ----
  float* red = (float*)SM;   // 4 pos x 8192 f32 = 128 KB
  __syncthreads();
  if (grp == 1) {
    #pragma unroll
    for (int mi = 0; mi < 8; ++mi)
      #pragma unroll
      for (int ni = 0; ni < 4; ++ni)
        *(f32x4*)&red[pos * 8192 + (mi * 4 + ni) * 256 + lane * 4] = acc[mi][ni];
  }
  __syncthreads();
  if (grp == 0) {
    const float nwv = nw[0];
    const int mrow = (lane >> 4) << 2;
    #pragma unroll
    for (int mi = 0; mi < 8; ++mi) {
      #pragma unroll
      for (int ni = 0; ni < 4; ++ni) {
        f32x4 other = *(const f32x4*)&red[pos * 8192 + (mi * 4 + ni) * 256 + lane * 4];
        f32x4 a = acc[mi][ni] + other;
        int mg = m0 + wm + ni * 16 + lrow;
        int hw = mg & 1023;
        float nz = nwv * noise[b * 1024 + hw];
        #pragma unroll
        for (int r = 0; r < 4; ++r) {
          int og = o0 + wo + mi * 16 + mrow + r;
          float v = a[r] * dsc[b * 512 + og] + nz + abias[og];
          v = (v > 0.f ? v : 0.2f * v) * 1.4142135623730951f;
          out[(size_t)(b * 512 + og) * 1024 + hw] = v;
        }
      }
    }
  }
}

extern "C" void kernel_launch(void* const* d_in, const int* in_sizes, int n_in,
                              void* d_out, int out_size, void* d_ws, size_t ws_size,
                              hipStream_t stream) {
  const float* x      = (const float*)d_in[0];
  const float* style  = (const float*)d_in[1];
  const float* noise  = (const float*)d_in[2];
  const float* weight = (const float*)d_in[3];
  const float* mod_w  = (const float*)d_in[4];
  const float* mod_b  = (const float*)d_in[5];
  const float* nw     = (const float*)d_in[6];
  const float* abias  = (const float*)d_in[7];
  float* out = (float*)d_out;

  char* ws = (char*)d_ws;
  float* s_buf = (float*)(ws + WS_S);
  float* dsc   = (float*)(ws + WS_DSC);
  float* wsq   = (float*)(ws + WS_WSQ);
  u16*   wbt   = (u16*)(ws + WS_WBT);
  u16*   xsp   = (u16*)(ws + WS_XSP);

  k_halo  <<<dim3(132, 16), 256, 0, stream>>>(xsp);
  k_style <<<2048, 256, 0, stream>>>(style, mod_w, mod_b, s_buf);
  k_wprep <<<1024, 256, 0, stream>>>(weight, wsq, wbt);
  k_dscale<<<2048, 256, 0, stream>>>(wsq, s_buf, dsc);
  k_xs    <<<dim3(8, 32, 16), 256, 0, stream>>>(x, s_buf, xsp);
  k_conv  <<<256, 512, 0, stream>>>(wbt, xsp, dsc, noise, nw, abias, out);
}

// Round 6
// 105.216 us; speedup vs baseline: 1.9130x; 1.9130x over previous
//
#include <hip/hip_runtime.h>
#include <cstdint>
#include <cstddef>

typedef unsigned short u16;
typedef __attribute__((ext_vector_type(8))) short short8;
typedef __attribute__((ext_vector_type(4))) float f32x4;

#define CIN   512
#define COUT  512
#define BATCH 16
#define HWSZ  1024      // 32*32
#define PADW  34        // 32 + 2 halo

static constexpr float MOD_SCALE  = 0.044194173824159216f;   // 1/sqrt(512)
static constexpr float CONV_SCALE = 0.014731391274719739f;   // 1/sqrt(512*9)

// workspace layout (bytes)
#define WS_S    0                              // 8192 f32   (32 KB)
#define WS_DSC  (32*1024)                      // 8192 f32   (32 KB)
#define WS_WSQ  (64*1024)                      // 262144 f32 (1 MB)
#define WS_WBT  (64*1024 + 1024*1024)          // 9*512*512 bf16 (4.5 MB)
#define WS_XSP  (WS_WBT + 9*512*512*2)         // 16*34*34*512 bf16 (~18 MB)

__device__ __forceinline__ u16 f2bf(float f) {
  union { float f; uint32_t u; } v; v.f = f;
  uint32_t r = v.u + 0x7fffu + ((v.u >> 16) & 1u);   // RNE
  return (u16)(r >> 16);
}

__device__ __forceinline__ void gload16(const void* g, void* l) {
  __builtin_amdgcn_global_load_lds(
      (const __attribute__((address_space(1))) void*)g,
      (__attribute__((address_space(3))) void*)l, 16, 0, 0);
}

// ---------------- s[b,i] = mod_scale * style[b,:] . mod_w[i,:] + mod_b[i] ----------------
__global__ void k_style(const float* __restrict__ style, const float* __restrict__ mod_w,
                        const float* __restrict__ mod_b, float* __restrict__ s_out) {
  int gid  = blockIdx.x * blockDim.x + threadIdx.x;
  int w    = gid >> 6, lane = gid & 63;
  int b    = w >> 9, i = w & 511;
  const float4* st = (const float4*)(style + (size_t)b * 512);
  const float4* mw = (const float4*)(mod_w + (size_t)i * 512);
  float4 a0 = st[lane * 2], a1 = st[lane * 2 + 1];
  float4 w0 = mw[lane * 2], w1 = mw[lane * 2 + 1];
  float acc = a0.x*w0.x + a0.y*w0.y + a0.z*w0.z + a0.w*w0.w
            + a1.x*w1.x + a1.y*w1.y + a1.z*w1.z + a1.w*w1.w;
  #pragma unroll
  for (int off = 32; off; off >>= 1) acc += __shfl_xor(acc, off);
  if (lane == 0) s_out[w] = acc * MOD_SCALE + mod_b[i];
}

// ---- fused: wsq[o,i] = sum_k w^2 ; wbt2[((kxy*64 + i/8)*512 + o)*8 + i%8] = bf16(w) ----
// A-fragment layout for direct global->VGPR MFMA loads: 16 consecutive o-rows give
// 16 x 16B contiguous (coalesced), k is 16B-chunk-major.
__global__ void k_wprep(const float* __restrict__ w, float* __restrict__ wsq,
                        u16* __restrict__ wbt2) {
  int idx = blockIdx.x * 256 + threadIdx.x;          // 262144 = o*512+i
  int o = idx >> 9, i = idx & 511;
  const float* p = w + (size_t)idx * 9;
  float a = 0.f;
  #pragma unroll
  for (int kxy = 0; kxy < 9; ++kxy) {
    float v = p[kxy];
    a += v * v;
    wbt2[((size_t)(kxy * 64 + (i >> 3)) * 512 + o) * 8 + (i & 7)] = f2bf(v);
  }
  wsq[idx] = a;
}

// ---------------- dscale[b,o] = conv_scale * rsqrt(cs^2 * sum_i wsq[o,i]*s[b,i]^2 + 1e-8) ----
__global__ void k_dscale(const float* __restrict__ wsq, const float* __restrict__ s,
                         float* __restrict__ dsc) {
  int gid  = blockIdx.x * blockDim.x + threadIdx.x;
  int w    = gid >> 6, lane = gid & 63;
  int b    = w >> 9, o = w & 511;
  const float4* q4 = (const float4*)(wsq + (size_t)o * 512);
  const float4* s4 = (const float4*)(s   + (size_t)b * 512);
  float4 q0 = q4[lane * 2], q1 = q4[lane * 2 + 1];
  float4 t0 = s4[lane * 2], t1 = s4[lane * 2 + 1];
  float acc = q0.x*t0.x*t0.x + q0.y*t0.y*t0.y + q0.z*t0.z*t0.z + q0.w*t0.w*t0.w
            + q1.x*t1.x*t1.x + q1.y*t1.y*t1.y + q1.z*t1.z*t1.z + q1.w*t1.w*t1.w;
  #pragma unroll
  for (int off = 32; off; off >>= 1) acc += __shfl_xor(acc, off);
  if (lane == 0)
    dsc[w] = CONV_SCALE * rsqrtf(acc * CONV_SCALE * CONV_SCALE + 1e-8f);
}

// ---------------- zero only the halo border of xs_p ----------------
__global__ void k_halo(u16* __restrict__ xsp) {
  int cell = blockIdx.x;      // 0..131 border cells of the 34x34 grid
  int b = blockIdx.y;
  int y, x;
  if (cell < 34)       { y = 0;          x = cell; }
  else if (cell < 68)  { y = 33;         x = cell - 34; }
  else if (cell < 100) { y = cell - 67;  x = 0; }    // 1..32
  else                 { y = cell - 99;  x = 33; }   // 1..32
  uint32_t* p = (uint32_t*)(xsp + ((size_t)(b * PADW + y) * PADW + x) * 512);
  p[threadIdx.x] = 0;   // 256 threads x 4B = 512 u16
}

// ---------------- xs_p[b][y+1][x+1][i] = bf16(x[b][i][y][x] * s[b][i])  (NCHW->NHWC) --------
__global__ void k_xs(const float* __restrict__ x, const float* __restrict__ s,
                     u16* __restrict__ xsp) {
  __shared__ float tile[64][33];
  int icb = blockIdx.x, y = blockIdx.y, b = blockIdx.z;
  int t = threadIdx.x;
  int i0 = icb * 64;
  int c  = t & 31;       // x coord
  int r0 = t >> 5;       // 0..7
  #pragma unroll
  for (int it = 0; it < 8; ++it) {
    int row = r0 + it * 8;                           // i_loc 0..63
    float sv = s[b * 512 + i0 + row];
    tile[row][c] = x[((size_t)(b * 512 + i0 + row)) * 1024 + y * 32 + c] * sv;
  }
  __syncthreads();
  int il = t & 63;
  int x0 = t >> 6;       // 0..3
  #pragma unroll
  for (int it = 0; it < 8; ++it) {
    int xc = x0 + it * 4;
    xsp[((size_t)((b * PADW + y + 1) * PADW) + (xc + 1)) * 512 + i0 + il] = f2bf(tile[il][xc]);
  }
}

// ---------------- implicit-GEMM conv + fused epilogue ----------------
// Tile 256(o) x 128(m), 8 waves (4o x 2m, per-wave 64x64), K=4608 in 72 steps of 64.
// A (weights, L2-resident per XCD) loads GLOBAL->VGPR directly, double-banked
// (av0/av1), pipelined 1 step ahead. B tri-buffered in LDS (T2 swizzled),
// staged with global_load_lds. Counted vmcnt(8) per step: drains av(ks)+B(ks+1),
// leaves av(ks+1) in flight. B stage issued AFTER the barrier (WAR-safe).
// LDS reads halved vs R4: 64 ds_read_b128/CU/step (768cy) < MFMA floor (1242cy).
__global__ __launch_bounds__(512, 2) void k_conv(
    const u16* __restrict__ wbt2, const u16* __restrict__ xsp,
    const float* __restrict__ dsc, const float* __restrict__ noise,
    const float* __restrict__ nw, const float* __restrict__ abias,
    float* __restrict__ out)
{
  __shared__ u16 Bld[3 * 8192];    // 3 x 128x64 bf16 = 48 KB (swizzled)

  const int tid  = threadIdx.x;
  const int wave = tid >> 6, lane = tid & 63;

  // T1: XCD swizzle (grid 256 = 8 XCD x 32 contiguous tiles; same-o0 per XCD half)
  const int bid = blockIdx.x;
  const int swz = (bid & 7) * 32 + (bid >> 3);
  const int o0 = (swz >> 7) << 8;     // 0 or 256
  const int m0 = (swz & 127) << 7;    // 0..16256
  const int b  = m0 >> 10;            // uniform per block

  const int wo = (wave >> 1) * 64;    // o sub-block: 0/64/128/192
  const int wm = (wave & 1) * 64;     // m sub-block: 0/64
  const int lrow = lane & 15;
  const int lk   = (lane >> 4) * 8;
  const int rsw  = (lrow & 7) << 3;   // read-side swizzle (u16 units)

  // ---- A: per-lane global base into wbt2 fragment layout ----
  // addr(ks,kh,mi) = pA + (ks>>3)*262144 + (ks&7)*32768 + kh*16384 + mi*128
  const u16* pA = wbt2 + (size_t)(lane >> 4) * 4096 + (size_t)(o0 + wo + lrow) * 8;

  // ---- B staging bases (global_load_lds): row = wave*16+q*8+(lane>>3),
  //      swizzled source chunk = (lane&7) ^ (row&7)  [T2] ----
  const int cc = (((lane & 7) ^ (lane >> 3)) * 8);
  const u16* gB[2]; int lBo[2];
  #pragma unroll
  for (int q = 0; q < 2; ++q) {
    int r = wave * 16 + q * 8 + (lane >> 3);          // 0..127
    int mg = m0 + r;
    int yy = (mg >> 5) & 31, xx = mg & 31;
    gB[q] = xsp + ((size_t)(b * PADW + yy) * PADW + xx) * 512 + cc;
    lBo[q] = (wave * 16 + q * 8) * 64;
  }

  f32x4 acc[4][4];
  #pragma unroll
  for (int i = 0; i < 4; ++i)
    #pragma unroll
    for (int j = 0; j < 4; ++j) acc[i][j] = (f32x4){0.f, 0.f, 0.f, 0.f};

  short8 av0[2][4], av1[2][4];   // double-banked A fragments (64 VGPR)

  auto avload = [&](int ks, short8 (&dst)[2][4]) {
    const u16* base = pA + (size_t)(ks >> 3) * 262144 + (size_t)(ks & 7) * 32768;
    #pragma unroll
    for (int kh = 0; kh < 2; ++kh)
      #pragma unroll
      for (int mi = 0; mi < 4; ++mi)
        dst[kh][mi] = *(const short8*)(base + kh * 16384 + mi * 128);
  };

  auto stageB = [&](int ks, int bufi) {
    int kxy = ks >> 3, ib = (ks & 7) << 6;
    int ky = kxy / 3, kx = kxy - ky * 3;
    int offB = ((ky * PADW + kx) << 9) + ib;
    int sb = bufi * 8192;
    #pragma unroll
    for (int q = 0; q < 2; ++q) gload16(gB[q] + offB, &Bld[sb + lBo[q]]);
  };

  auto compute = [&](const short8 (&av)[2][4], int bufi) {
    const int cb = bufi * 8192;
    __builtin_amdgcn_s_setprio(1);
    #pragma unroll
    for (int kh = 0; kh < 2; ++kh) {
      int kos = (kh * 32 + lk) ^ rsw;
      short8 bv[4];
      #pragma unroll
      for (int ni = 0; ni < 4; ++ni)
        bv[ni] = *(const short8*)&Bld[cb + (wm + ni * 16 + lrow) * 64 + kos];
      #pragma unroll
      for (int mi = 0; mi < 4; ++mi)
        #pragma unroll
        for (int ni = 0; ni < 4; ++ni)
          acc[mi][ni] = __builtin_amdgcn_mfma_f32_16x16x32_bf16(
              av[kh][mi], bv[ni], acc[mi][ni], 0, 0, 0);
    }
    __builtin_amdgcn_s_setprio(0);
  };

  // prologue: B(0)->buf0, B(1)->buf1, A(0)->av0. FIFO: [B0(2), B1(2), A0(8)]
  stageB(0, 0);
  stageB(1, 1);
  avload(0, av0);

  // Step ks: issue av(ks+1) -> other bank; vmcnt(8) [drains av(ks)+B(ks+1),
  // leaves av(ks+1)]; barrier [all waves done compute(ks-1) -> buf (ks+2)%3
  // overwrite safe]; issue B(ks+2); compute(ks).
#define STEP(KS, AVCUR, AVNXT, BBUF, BNXT, DOAV, DOSTAGE, WN)            \
  {                                                                      \
    if (DOAV) avload((KS) + 1, AVNXT);                                   \
    __builtin_amdgcn_sched_barrier(0);                                   \
    asm volatile("s_waitcnt vmcnt(" #WN ")" ::: "memory");               \
    __builtin_amdgcn_s_barrier();                                        \
    __builtin_amdgcn_sched_barrier(0);                                   \
    if (DOSTAGE) stageB((KS) + 2, BNXT);                                 \
    compute(AVCUR, BBUF);                                                \
  }

  for (int t = 0; t < 11; ++t) {
    const int k0 = t * 6;                    // ks+2 <= 67 inside: no guards
    STEP(k0 + 0, av0, av1, 0, 2, 1, 1, 8);
    STEP(k0 + 1, av1, av0, 1, 0, 1, 1, 8);
    STEP(k0 + 2, av0, av1, 2, 1, 1, 1, 8);
    STEP(k0 + 3, av1, av0, 0, 2, 1, 1, 8);
    STEP(k0 + 4, av0, av1, 1, 0, 1, 1, 8);
    STEP(k0 + 5, av1, av0, 2, 1, 1, 1, 8);
  }
  // tail ks = 66..71
  STEP(66, av0, av1, 0, 2, 1, 1, 8);
  STEP(67, av1, av0, 1, 0, 1, 1, 8);
  STEP(68, av0, av1, 2, 1, 1, 1, 8);
  STEP(69, av1, av0, 0, 2, 1, 1, 8);   // B(71) -> buf2
  STEP(70, av0, av1, 1, 0, 1, 0, 8);   // no B(72)
  STEP(71, av1, av0, 2, 1, 0, 0, 0);   // drain remaining av(71)
#undef STEP

  // epilogue: demod*conv_scale, noise, bias, leaky(0.2)*sqrt(2)
  const float nwv = nw[0];
  const int mrow = (lane >> 4) << 2;
  #pragma unroll
  for (int mi = 0; mi < 4; ++mi) {
    #pragma unroll
    for (int ni = 0; ni < 4; ++ni) {
      int mg = m0 + wm + ni * 16 + lrow;
      int hw = mg & 1023;
      float nz = nwv * noise[b * 1024 + hw];
      #pragma unroll
      for (int r = 0; r < 4; ++r) {
        int og = o0 + wo + mi * 16 + mrow + r;
        float v = acc[mi][ni][r] * dsc[b * 512 + og] + nz + abias[og];
        v = (v > 0.f ? v : 0.2f * v) * 1.4142135623730951f;
        out[(size_t)(b * 512 + og) * 1024 + hw] = v;
      }
    }
  }
}

extern "C" void kernel_launch(void* const* d_in, const int* in_sizes, int n_in,
                              void* d_out, int out_size, void* d_ws, size_t ws_size,
                              hipStream_t stream) {
  const float* x      = (const float*)d_in[0];
  const float* style  = (const float*)d_in[1];
  const float* noise  = (const float*)d_in[2];
  const float* weight = (const float*)d_in[3];
  const float* mod_w  = (const float*)d_in[4];
  const float* mod_b  = (const float*)d_in[5];
  const float* nw     = (const float*)d_in[6];
  const float* abias  = (const float*)d_in[7];
  float* out = (float*)d_out;

  char* ws = (char*)d_ws;
  float* s_buf = (float*)(ws + WS_S);
  float* dsc   = (float*)(ws + WS_DSC);
  float* wsq   = (float*)(ws + WS_WSQ);
  u16*   wbt2  = (u16*)(ws + WS_WBT);
  u16*   xsp   = (u16*)(ws + WS_XSP);

  k_halo  <<<dim3(132, 16), 256, 0, stream>>>(xsp);
  k_style <<<2048, 256, 0, stream>>>(style, mod_w, mod_b, s_buf);
  k_wprep <<<1024, 256, 0, stream>>>(weight, wsq, wbt2);
  k_dscale<<<2048, 256, 0, stream>>>(wsq, s_buf, dsc);
  k_xs    <<<dim3(8, 32, 16), 256, 0, stream>>>(x, s_buf, xsp);
  k_conv  <<<256, 512, 0, stream>>>(wbt2, xsp, dsc, noise, nw, abias, out);
}